// Round 4
// baseline (346.799 us; speedup 1.0000x reference)
//
#include <hip/hip_runtime.h>
#include <hip/hip_bf16.h>
#include <math.h>

#define B_   8
#define CIN  32
#define COUT 64
#define KK_  4
#define DD   32
#define HH   64
#define WW   64
#define HW   (HH*WW)        // 4096
#define DHW  (DD*HH*WW)     // 131072

typedef __attribute__((ext_vector_type(8)))  short bf16x8;
typedef __attribute__((ext_vector_type(16))) float f32x16;

__device__ __forceinline__ unsigned short f2bf(float f) {
    union { float f; unsigned int u; } v; v.f = f;
    return (unsigned short)((v.u + 0x7FFFu + ((v.u >> 16) & 1u)) >> 16);   // RNE
}
__device__ __forceinline__ float bf2f(unsigned short s) {
    union { unsigned int u; float f; } v; v.u = ((unsigned int)s) << 16;
    return v.f;
}
__device__ __forceinline__ void gll16(const void* g, void* l) {
    __builtin_amdgcn_global_load_lds(
        (const __attribute__((address_space(1))) void*)g,
        (__attribute__((address_space(3))) void*)l, 16, 0, 0);
}

// ---------------- 1) transpose x -> bf16 xt rows: [b][d][h] x [oct4][w64 swz][8ci]
// swizzle: 16B chunk for w stored at byte (w*16)^(oct<<4) within its 1024B oct section.
__global__ __launch_bounds__(256) void transpose_kernel(const float* __restrict__ x,
                                                        unsigned short* __restrict__ xt) {
    const int t = threadIdx.x;
    const int r = t >> 6, w = t & 63;
    const int h = (blockIdx.x << 2) + r;
    const int d = blockIdx.y, b = blockIdx.z;

    const float* xb = x + (size_t)b*CIN*DHW + (size_t)d*HW + (size_t)h*WW + w;
    unsigned int packed[CIN/2];
    #pragma unroll
    for (int c2 = 0; c2 < CIN/2; ++c2) {
        unsigned int lo = f2bf(xb[(size_t)(2*c2)   * DHW]);
        unsigned int hi = f2bf(xb[(size_t)(2*c2+1) * DHW]);
        packed[c2] = lo | (hi << 16);
    }
    char* row = (char*)xt + (size_t)((b*DD + d)*HH + h) * 4096;
    #pragma unroll
    for (int q = 0; q < 4; ++q) {
        uint4 v = make_uint4(packed[4*q], packed[4*q+1], packed[4*q+2], packed[4*q+3]);
        *(uint4*)(row + q*1024 + (((w << 4)) ^ (q << 4))) = v;
    }
}

// ---------------- 2) pooling partials from xt: pblk[b][d][ci] ----------------
__global__ __launch_bounds__(256) void pool2_kernel(const unsigned short* __restrict__ xt,
                                                    float* __restrict__ pblk) {
    const int t = threadIdx.x;
    const int oct = t >> 6, wi = t & 63;       // each wave owns one ci-oct
    const int d = blockIdx.x, b = blockIdx.y;
    const char* base = (const char*)xt + (size_t)((b*DD + d)*HH) * 4096 + oct*1024 + wi*16;
    float acc[8];
    #pragma unroll
    for (int j = 0; j < 8; ++j) acc[j] = 0.f;
    for (int h = 0; h < HH; ++h) {
        bf16x8 v = *(const bf16x8*)(base + (size_t)h * 4096);
        #pragma unroll
        for (int j = 0; j < 8; ++j) acc[j] += bf2f((unsigned short)v[j]);
    }
    #pragma unroll
    for (int off = 32; off > 0; off >>= 1) {
        #pragma unroll
        for (int j = 0; j < 8; ++j) acc[j] += __shfl_xor(acc[j], off);
    }
    if ((t & 63) == 0) {
        #pragma unroll
        for (int j = 0; j < 8; ++j)
            pblk[(b*DD + d)*CIN + oct*8 + j] = acc[j];
    }
}

// ---------------- 3) attention MLP + softmax + agg bias ----------------
__device__ __forceinline__ float gelu_erf(float v) {
    return 0.5f * v * (1.f + erff(v * 0.70710678118654752f));
}

__global__ void attn_kernel(const float* __restrict__ pblk,
                            const float* __restrict__ temperature,
                            const float* __restrict__ bn1_g, const float* __restrict__ bn1_b,
                            const float* __restrict__ w1,    const float* __restrict__ b1,
                            const float* __restrict__ bn2_g, const float* __restrict__ bn2_b,
                            const float* __restrict__ w2,    const float* __restrict__ b2,
                            const float* __restrict__ bn3_g, const float* __restrict__ bn3_b,
                            const float* __restrict__ w3,    const float* __restrict__ b3,
                            const float* __restrict__ cbias,
                            float* __restrict__ attn_out, float* __restrict__ aggb_out) {
    __shared__ float A[B_][CIN], A2[B_][CIN];
    __shared__ float L[B_][KK_], ATT[B_][KK_];
    const int t = threadIdx.x;          // 256 threads: b*32 + c
    const int b = t >> 5, c = t & 31;

    float pv = 0.f;
    for (int dd = 0; dd < DD; ++dd) pv += pblk[(b*DD + dd)*CIN + c];
    pv *= (1.f / (float)DHW);

    A[b][c] = gelu_erf(pv * bn1_g[c] + bn1_b[c]);
    __syncthreads();

    float s = b1[c];
    for (int j = 0; j < CIN; ++j) s += A[b][j] * w1[c*CIN + j];
    A2[b][c] = gelu_erf(s * bn2_g[c] + bn2_b[c]);
    __syncthreads();

    float s2 = b2[c];
    for (int j = 0; j < CIN; ++j) s2 += A2[b][j] * w2[c*CIN + j];
    s2 += pv;                              // residual
    s2 = s2 * bn3_g[c] + bn3_b[c];
    __syncthreads();
    A[b][c] = s2;
    __syncthreads();

    if (c < KK_) {
        float lv = b3[c];
        for (int j = 0; j < CIN; ++j) lv += A[b][j] * w3[c*CIN + j];
        L[b][c] = lv;
    }
    __syncthreads();

    const float T = temperature[0];
    if (c < KK_) {
        float m = fmaxf(fmaxf(L[b][0], L[b][1]), fmaxf(L[b][2], L[b][3]));
        float e = expf((L[b][c] - m) / T);
        float den = 0.f;
        for (int j = 0; j < KK_; ++j) den += expf((L[b][j] - m) / T);
        float av = e / den;
        ATT[b][c] = av;
        attn_out[b*KK_ + c] = av;
    }
    __syncthreads();

    for (int o = c; o < COUT; o += CIN) {
        float sb = 0.f;
        for (int k = 0; k < KK_; ++k) sb += ATT[b][k] * cbias[k*COUT + o];
        aggb_out[b*COUT + o] = sb;
    }
}

// ---------------- 4) aggregate weights -> bf16 wt[b][kpos][co][ci] ----------------
__global__ void aggw_kernel(const float* __restrict__ weight,   // [K][O][CI][27]
                            const float* __restrict__ attn,     // [B][K]
                            unsigned short* __restrict__ wt) {  // [B][27][O][CI] bf16
    const int idx = blockIdx.x * 256 + threadIdx.x;   // B*27*64*32 = 442368
    const int ci   = idx & 31;
    const int co   = (idx >> 5) & 63;
    int r          = idx >> 11;
    const int kpos = r % 27;
    const int b    = r / 27;
    float s = 0.f;
    #pragma unroll
    for (int k = 0; k < KK_; ++k)
        s += attn[b*KK_ + k] * weight[((k*COUT + co)*CIN + ci)*27 + kpos];
    wt[idx] = f2bf(s);
}

// ---------------- 5) MFMA conv, d-streaming pipeline ----------------
// grid (HH/2, DD/16, B); block 256 = 4 waves (hv x dv); 1 block/CU (128 KiB LDS).
// LDS ring: 8 zd-slots x 4 yh-rows x 4096 B. Per step: compute d-pair, prefetch 2 slabs.
__global__ __launch_bounds__(256) void conv_mfma(const unsigned short* __restrict__ xt,
                                                 const unsigned short* __restrict__ wt,
                                                 const float* __restrict__ aggb,
                                                 float* __restrict__ out) {
    __shared__ char smem[8 * 16384];
    const int t = threadIdx.x;
    const int lane = t & 63, wv = t >> 6;
    const int lw = lane & 31, lh = lane >> 5;
    const int hv = wv & 1, dv = wv >> 1;
    const int h0 = blockIdx.x << 1;
    const int d0 = blockIdx.y << 4;
    const int b  = blockIdx.z;

    const char* xb = (const char*)xt + (size_t)(b*DD)*HH*4096;
    const int yh_st = h0 - 1 + wv;     // row this wave stages
    const bool yh_ok = ((unsigned)yh_st < HH);

    // stage slab zd into slot (zd&7); wave wv handles row wv. Wave-uniform branches.
    auto stage = [&](int zd) {
        char* ldsrow = &smem[((zd & 7) << 14) + (wv << 12)];
        if (((unsigned)zd < DD) && yh_ok) {
            const char* src = xb + (size_t)(zd*HH + yh_st)*4096 + lane*16;
            #pragma unroll
            for (int i = 0; i < 4; ++i)
                gll16(src + i*1024, ldsrow + i*1024);
        } else if (zd <= DD) {         // in read range but OOB -> zero row
            #pragma unroll
            for (int i = 0; i < 4; ++i)
                *(uint4*)(ldsrow + i*1024 + lane*16) = make_uint4(0u,0u,0u,0u);
        }
    };

    const char* wtb = (const char*)wt + (size_t)b * 27 * 4096;
    const int a_off = lw*64 + lh*16;
    const int o0 = lh, o1 = 2 + lh;
    const bf16x8 bz = {};

    // bias folded into accumulator init
    f32x16 binit0, binit1;
    #pragma unroll
    for (int reg = 0; reg < 16; ++reg) {
        const int cr = (reg & 3) + ((reg >> 2) << 3) + (lh << 2);
        binit0[reg] = aggb[b*COUT + cr];
        binit1[reg] = aggb[b*COUT + 32 + cr];
    }

    // prologue: slabs for first d-pair
    stage(d0 - 1); stage(d0); stage(d0 + 1); stage(d0 + 2);
    __syncthreads();

    const int h = h0 + hv;

    for (int s = 0; s < 8; ++s) {
        const int d = d0 + (s << 1);
        if (s < 7) { stage(d + 3); stage(d + 4); }   // prefetch next pair's slabs

        const int dmy = d + dv;
        f32x16 acc[2][2];
        acc[0][0] = binit0; acc[0][1] = binit0;
        acc[1][0] = binit1; acc[1][1] = binit1;

        #pragma unroll
        for (int kd = 0; kd < 3; ++kd) {
            const int zd = dmy + kd - 1;
            const int sb = (zd & 7) << 14;
            #pragma unroll
            for (int kh = 0; kh < 3; ++kh) {
                const int rb = sb + ((hv + kh) << 12);
                const char* wk0 = wtb + (size_t)((kd*3 + kh)*3) * 4096;
                #pragma unroll
                for (int kw = 0; kw < 3; ++kw) {
                    const char* wk = wk0 + (size_t)kw * 4096;
                    const bf16x8 a00 = *(const bf16x8*)(wk + a_off);
                    const bf16x8 a01 = *(const bf16x8*)(wk + 32 + a_off);
                    const bf16x8 a10 = *(const bf16x8*)(wk + 2048 + a_off);
                    const bf16x8 a11 = *(const bf16x8*)(wk + 2048 + 32 + a_off);
                    #pragma unroll
                    for (int fs = 0; fs < 2; ++fs) {
                        const int wp = (fs << 5) + lw + kw - 1;
                        const bool oob = ((unsigned)wp >= (unsigned)WW);
                        const int wpc = oob ? ((wp < 0) ? 0 : (WW - 1)) : wp;
                        bf16x8 b0v = *(const bf16x8*)&smem[rb + o0*1024 + ((wpc << 4) ^ (o0 << 4))];
                        bf16x8 b1v = *(const bf16x8*)&smem[rb + o1*1024 + ((wpc << 4) ^ (o1 << 4))];
                        if (oob) { b0v = bz; b1v = bz; }
                        acc[0][fs] = __builtin_amdgcn_mfma_f32_32x32x16_bf16(a00, b0v, acc[0][fs], 0, 0, 0);
                        acc[1][fs] = __builtin_amdgcn_mfma_f32_32x32x16_bf16(a10, b0v, acc[1][fs], 0, 0, 0);
                        acc[0][fs] = __builtin_amdgcn_mfma_f32_32x32x16_bf16(a01, b1v, acc[0][fs], 0, 0, 0);
                        acc[1][fs] = __builtin_amdgcn_mfma_f32_32x32x16_bf16(a11, b1v, acc[1][fs], 0, 0, 0);
                    }
                }
            }
        }

        float* ob = out + (size_t)b*COUT*DHW + (size_t)(dmy*HH + h)*WW;
        #pragma unroll
        for (int reg = 0; reg < 16; ++reg) {
            const int cr = (reg & 3) + ((reg >> 2) << 3) + (lh << 2);
            ob[(size_t)cr*DHW + lw]             = acc[0][0][reg];
            ob[(size_t)cr*DHW + 32 + lw]        = acc[0][1][reg];
            ob[(size_t)(32 + cr)*DHW + lw]      = acc[1][0][reg];
            ob[(size_t)(32 + cr)*DHW + 32 + lw] = acc[1][1][reg];
        }
        __syncthreads();
    }
}

// ---------------- launch ----------------
extern "C" void kernel_launch(void* const* d_in, const int* in_sizes, int n_in,
                              void* d_out, int out_size, void* d_ws, size_t ws_size,
                              hipStream_t stream) {
    const float* x           = (const float*)d_in[0];
    const float* weight      = (const float*)d_in[1];
    const float* cbias       = (const float*)d_in[2];
    const float* temperature = (const float*)d_in[3];
    const float* bn1_g       = (const float*)d_in[4];
    const float* bn1_b       = (const float*)d_in[5];
    const float* w1          = (const float*)d_in[6];
    const float* b1          = (const float*)d_in[7];
    const float* bn2_g       = (const float*)d_in[8];
    const float* bn2_b       = (const float*)d_in[9];
    const float* w2          = (const float*)d_in[10];
    const float* b2          = (const float*)d_in[11];
    const float* bn3_g       = (const float*)d_in[12];
    const float* bn3_b       = (const float*)d_in[13];
    const float* w3          = (const float*)d_in[14];
    const float* b3          = (const float*)d_in[15];
    float* out = (float*)d_out;

    char* ws = (char*)d_ws;
    float*          attn = (float*)(ws + 1024);           // 32 f
    float*          aggb = (float*)(ws + 2048);           // 512 f
    float*          pblk = (float*)(ws + 16384);          // 8*32*32 f
    unsigned short* wt   = (unsigned short*)(ws + 65536); // 884736 B
    unsigned short* xt   = (unsigned short*)(ws + (1u << 20)); // 64 MiB

    transpose_kernel<<<dim3(HH/4, DD, B_), 256, 0, stream>>>(x, xt);
    pool2_kernel<<<dim3(DD, B_), 256, 0, stream>>>(xt, pblk);
    attn_kernel<<<1, 256, 0, stream>>>(pblk, temperature,
                                       bn1_g, bn1_b, w1, b1,
                                       bn2_g, bn2_b, w2, b2,
                                       bn3_g, bn3_b, w3, b3,
                                       cbias, attn, aggb);
    aggw_kernel<<<(B_*27*COUT*CIN)/256, 256, 0, stream>>>(weight, attn, wt);
    conv_mfma<<<dim3(HH/2, DD/16, B_), 256, 0, stream>>>(xt, wt, aggb, out);
}

// Round 5
// 191.286 us; speedup vs baseline: 1.8130x; 1.8130x over previous
//
#include <hip/hip_runtime.h>
#include <hip/hip_bf16.h>
#include <math.h>

#define B_   8
#define CIN  32
#define COUT 64
#define KK_  4
#define DD   32
#define HH   64
#define WW   64
#define HW   (HH*WW)        // 4096
#define DHW  (DD*HH*WW)     // 131072

typedef __attribute__((ext_vector_type(8)))  short bf16x8;
typedef __attribute__((ext_vector_type(16))) float f32x16;

__device__ __forceinline__ unsigned short f2bf(float f) {
    union { float f; unsigned int u; } v; v.f = f;
    return (unsigned short)((v.u + 0x7FFFu + ((v.u >> 16) & 1u)) >> 16);   // RNE
}
__device__ __forceinline__ float bf2f(unsigned short s) {
    union { unsigned int u; float f; } v; v.u = ((unsigned int)s) << 16;
    return v.f;
}
__device__ __forceinline__ void gll16(const void* g, void* l) {
    __builtin_amdgcn_global_load_lds(
        (const __attribute__((address_space(1))) void*)g,
        (__attribute__((address_space(3))) void*)l, 16, 0, 0);
}

// ---------------- 1) transpose x -> bf16 xt rows: [b][d][h] x [oct4][w64 swz][8ci]
// swizzle: 16B chunk for w stored at byte (w*16)^(oct<<4) within its 1024B oct section.
__global__ __launch_bounds__(256) void transpose_kernel(const float* __restrict__ x,
                                                        unsigned short* __restrict__ xt) {
    const int t = threadIdx.x;
    const int r = t >> 6, w = t & 63;
    const int h = (blockIdx.x << 2) + r;
    const int d = blockIdx.y, b = blockIdx.z;

    const float* xb = x + (size_t)b*CIN*DHW + (size_t)d*HW + (size_t)h*WW + w;
    unsigned int packed[CIN/2];
    #pragma unroll
    for (int c2 = 0; c2 < CIN/2; ++c2) {
        unsigned int lo = f2bf(xb[(size_t)(2*c2)   * DHW]);
        unsigned int hi = f2bf(xb[(size_t)(2*c2+1) * DHW]);
        packed[c2] = lo | (hi << 16);
    }
    char* row = (char*)xt + (size_t)((b*DD + d)*HH + h) * 4096;
    #pragma unroll
    for (int q = 0; q < 4; ++q) {
        uint4 v = make_uint4(packed[4*q], packed[4*q+1], packed[4*q+2], packed[4*q+3]);
        *(uint4*)(row + q*1024 + (((w << 4)) ^ (q << 4))) = v;
    }
}

// ---------------- 2) pooling partials from xt: pblk[b][d][ci] ----------------
__global__ __launch_bounds__(256) void pool2_kernel(const unsigned short* __restrict__ xt,
                                                    float* __restrict__ pblk) {
    const int t = threadIdx.x;
    const int oct = t >> 6, wi = t & 63;
    const int d = blockIdx.x, b = blockIdx.y;
    const char* base = (const char*)xt + (size_t)((b*DD + d)*HH) * 4096 + oct*1024 + wi*16;
    float acc[8];
    #pragma unroll
    for (int j = 0; j < 8; ++j) acc[j] = 0.f;
    for (int h = 0; h < HH; ++h) {
        bf16x8 v = *(const bf16x8*)(base + (size_t)h * 4096);
        #pragma unroll
        for (int j = 0; j < 8; ++j) acc[j] += bf2f((unsigned short)v[j]);
    }
    #pragma unroll
    for (int off = 32; off > 0; off >>= 1) {
        #pragma unroll
        for (int j = 0; j < 8; ++j) acc[j] += __shfl_xor(acc[j], off);
    }
    if ((t & 63) == 0) {
        #pragma unroll
        for (int j = 0; j < 8; ++j)
            pblk[(b*DD + d)*CIN + oct*8 + j] = acc[j];
    }
}

// ---------------- 3) attention MLP + softmax + agg bias ----------------
__device__ __forceinline__ float gelu_erf(float v) {
    return 0.5f * v * (1.f + erff(v * 0.70710678118654752f));
}

__global__ void attn_kernel(const float* __restrict__ pblk,
                            const float* __restrict__ temperature,
                            const float* __restrict__ bn1_g, const float* __restrict__ bn1_b,
                            const float* __restrict__ w1,    const float* __restrict__ b1,
                            const float* __restrict__ bn2_g, const float* __restrict__ bn2_b,
                            const float* __restrict__ w2,    const float* __restrict__ b2,
                            const float* __restrict__ bn3_g, const float* __restrict__ bn3_b,
                            const float* __restrict__ w3,    const float* __restrict__ b3,
                            const float* __restrict__ cbias,
                            float* __restrict__ attn_out, float* __restrict__ aggb_out) {
    __shared__ float A[B_][CIN], A2[B_][CIN];
    __shared__ float L[B_][KK_], ATT[B_][KK_];
    const int t = threadIdx.x;
    const int b = t >> 5, c = t & 31;

    float pv = 0.f;
    for (int dd = 0; dd < DD; ++dd) pv += pblk[(b*DD + dd)*CIN + c];
    pv *= (1.f / (float)DHW);

    A[b][c] = gelu_erf(pv * bn1_g[c] + bn1_b[c]);
    __syncthreads();

    float s = b1[c];
    for (int j = 0; j < CIN; ++j) s += A[b][j] * w1[c*CIN + j];
    A2[b][c] = gelu_erf(s * bn2_g[c] + bn2_b[c]);
    __syncthreads();

    float s2 = b2[c];
    for (int j = 0; j < CIN; ++j) s2 += A2[b][j] * w2[c*CIN + j];
    s2 += pv;
    s2 = s2 * bn3_g[c] + bn3_b[c];
    __syncthreads();
    A[b][c] = s2;
    __syncthreads();

    if (c < KK_) {
        float lv = b3[c];
        for (int j = 0; j < CIN; ++j) lv += A[b][j] * w3[c*CIN + j];
        L[b][c] = lv;
    }
    __syncthreads();

    const float T = temperature[0];
    if (c < KK_) {
        float m = fmaxf(fmaxf(L[b][0], L[b][1]), fmaxf(L[b][2], L[b][3]));
        float e = expf((L[b][c] - m) / T);
        float den = 0.f;
        for (int j = 0; j < KK_; ++j) den += expf((L[b][j] - m) / T);
        float av = e / den;
        ATT[b][c] = av;
        attn_out[b*KK_ + c] = av;
    }
    __syncthreads();

    for (int o = c; o < COUT; o += CIN) {
        float sb = 0.f;
        for (int k = 0; k < KK_; ++k) sb += ATT[b][k] * cbias[k*COUT + o];
        aggb_out[b*COUT + o] = sb;
    }
}

// ---------------- 4) aggregate weights -> bf16 wt[b][kpos][co][ci] ----------------
__global__ void aggw_kernel(const float* __restrict__ weight,   // [K][O][CI][27]
                            const float* __restrict__ attn,     // [B][K]
                            unsigned short* __restrict__ wt) {  // [B][27][O][CI] bf16
    const int idx = blockIdx.x * 256 + threadIdx.x;
    const int ci   = idx & 31;
    const int co   = (idx >> 5) & 63;
    int r          = idx >> 11;
    const int kpos = r % 27;
    const int b    = r / 27;
    float s = 0.f;
    #pragma unroll
    for (int k = 0; k < KK_; ++k)
        s += attn[b*KK_ + k] * weight[((k*COUT + co)*CIN + ci)*27 + kpos];
    wt[idx] = f2bf(s);
}

// ---------------- 5) MFMA conv: R=4 d-batch, register B-cache ----------------
// grid (HH/4, DD/4, B); block 512 = 8 waves (wv2 x hv4).
// Wave: M=64 co, N=32 w (half wv), R=4 d-rows, h = h0+hv.
// LDS: 36 rows [zo 0..5][ho 0..5] x 4096 B = 144 KiB.
__global__ __launch_bounds__(512, 2) void conv_mfma(const unsigned short* __restrict__ xt,
                                                    const unsigned short* __restrict__ wt,
                                                    const float* __restrict__ aggb,
                                                    float* __restrict__ out) {
    __shared__ char smem[36 * 4096];
    const int t    = threadIdx.x;
    const int lane = t & 63;
    const int wid  = t >> 6;            // 0..7
    const int wv   = wid & 1;           // w-half
    const int hv   = wid >> 1;          // 0..3
    const int lw   = lane & 31, lh = lane >> 5;
    const int h0   = blockIdx.x << 2;
    const int d0   = blockIdx.y << 2;
    const int b    = blockIdx.z;

    const char* xb  = (const char*)xt + (size_t)(b*DD)*HH*4096;
    const char* wtb = (const char*)wt + (size_t)b * 27 * 4096;

    // stage one LDS row (zo,ho): all 64 lanes of the calling wave
    auto stage_row = [&](int zo, int ho) {
        const int zd = d0 - 1 + zo, yh = h0 - 1 + ho;
        char* dst = smem + (size_t)((zo*6 + ho) << 12);
        if ((unsigned)zd < DD && (unsigned)yh < HH) {
            const char* src = xb + (size_t)(zd*HH + yh)*4096 + lane*16;
            #pragma unroll
            for (int q = 0; q < 4; ++q) gll16(src + (q << 10), dst + (q << 10));
        } else {
            #pragma unroll
            for (int q = 0; q < 4; ++q)
                *(uint4*)(dst + (q << 10) + lane*16) = make_uint4(0u,0u,0u,0u);
        }
    };

    // batch A: rows ho 0..3 (24 rows, 3 per wave), ho-major rid = ho*6+zo
    #pragma unroll
    for (int i = 0; i < 3; ++i) {
        const int rid = wid*3 + i;          // 0..23
        stage_row(rid % 6, rid / 6);
    }
    __syncthreads();
    if (wid < 6) stage_row(wid, 4);         // batch B: ho=4, lands before kh=1 barrier

    f32x16 acc[4][2];
    #pragma unroll
    for (int r = 0; r < 4; ++r) {
        acc[r][0] = (f32x16){};
        acc[r][1] = (f32x16){};
    }

    const int a_off = lw*64 + lh*16;
    const bf16x8 bz = {};
    const int o0 = lh, o1 = 2 + lh;

    #pragma unroll
    for (int kh = 0; kh < 3; ++kh) {
        if (kh == 1) {
            __syncthreads();                // ho=4 rows landed
            if (wid < 6) stage_row(wid, 5); // batch C: ho=5, lands before kh=2 barrier
        }
        if (kh == 2) __syncthreads();       // ho=5 rows landed
        const int ho = hv + kh;             // 0..5
        #pragma unroll
        for (int kw = 0; kw < 3; ++kw) {
            const int wp  = (wv << 5) + lw + kw - 1;
            const bool oob = ((unsigned)wp >= (unsigned)WW);
            const int wpc = oob ? ((wp < 0) ? 0 : (WW - 1)) : wp;
            const int sw0 = (o0 << 10) + ((wpc << 4) ^ (o0 << 4));
            const int sw1 = (o1 << 10) + ((wpc << 4) ^ (o1 << 4));

            bf16x8 bc[6][2];                // register B-cache over zo
            #pragma unroll
            for (int zo = 0; zo < 6; ++zo) {
                const int rb = (zo*6 + ho) << 12;
                bf16x8 v0 = *(const bf16x8*)&smem[rb + sw0];
                bf16x8 v1 = *(const bf16x8*)&smem[rb + sw1];
                bc[zo][0] = oob ? bz : v0;
                bc[zo][1] = oob ? bz : v1;
            }
            #pragma unroll
            for (int kd = 0; kd < 3; ++kd) {
                const char* wk = wtb + (size_t)(((kd*3 + kh)*3 + kw) << 12);
                const bf16x8 a00 = *(const bf16x8*)(wk + a_off);
                const bf16x8 a01 = *(const bf16x8*)(wk + 32 + a_off);
                const bf16x8 a10 = *(const bf16x8*)(wk + 2048 + a_off);
                const bf16x8 a11 = *(const bf16x8*)(wk + 2048 + 32 + a_off);
                #pragma unroll
                for (int r = 0; r < 4; ++r) {
                    const int zo = r + kd;  // 0..5
                    acc[r][0] = __builtin_amdgcn_mfma_f32_32x32x16_bf16(a00, bc[zo][0], acc[r][0], 0, 0, 0);
                    acc[r][0] = __builtin_amdgcn_mfma_f32_32x32x16_bf16(a01, bc[zo][1], acc[r][0], 0, 0, 0);
                    acc[r][1] = __builtin_amdgcn_mfma_f32_32x32x16_bf16(a10, bc[zo][0], acc[r][1], 0, 0, 0);
                    acc[r][1] = __builtin_amdgcn_mfma_f32_32x32x16_bf16(a11, bc[zo][1], acc[r][1], 0, 0, 0);
                }
            }
        }
    }

    // epilogue: co = cb*32 + (reg&3) + 8*(reg>>2) + 4*lh ; w = wv*32+lw ; rows d0+r, h0+hv
    const float* ab = aggb + b*COUT;
    const int sp0 = (h0 + hv)*WW + (wv << 5) + lw;
    #pragma unroll
    for (int cb = 0; cb < 2; ++cb) {
        #pragma unroll
        for (int reg = 0; reg < 16; ++reg) {
            const int co = (cb << 5) + (reg & 3) + ((reg >> 2) << 3) + (lh << 2);
            const float bb = ab[co];
            float* oc = out + ((size_t)(b*COUT + co))*DHW + sp0;
            #pragma unroll
            for (int r = 0; r < 4; ++r)
                oc[(size_t)(d0 + r)*HW] = acc[r][cb][reg] + bb;
        }
    }
}

// ---------------- launch ----------------
extern "C" void kernel_launch(void* const* d_in, const int* in_sizes, int n_in,
                              void* d_out, int out_size, void* d_ws, size_t ws_size,
                              hipStream_t stream) {
    const float* x           = (const float*)d_in[0];
    const float* weight      = (const float*)d_in[1];
    const float* cbias       = (const float*)d_in[2];
    const float* temperature = (const float*)d_in[3];
    const float* bn1_g       = (const float*)d_in[4];
    const float* bn1_b       = (const float*)d_in[5];
    const float* w1          = (const float*)d_in[6];
    const float* b1          = (const float*)d_in[7];
    const float* bn2_g       = (const float*)d_in[8];
    const float* bn2_b       = (const float*)d_in[9];
    const float* w2          = (const float*)d_in[10];
    const float* b2          = (const float*)d_in[11];
    const float* bn3_g       = (const float*)d_in[12];
    const float* bn3_b       = (const float*)d_in[13];
    const float* w3          = (const float*)d_in[14];
    const float* b3          = (const float*)d_in[15];
    float* out = (float*)d_out;

    char* ws = (char*)d_ws;
    float*          attn = (float*)(ws + 1024);
    float*          aggb = (float*)(ws + 2048);
    float*          pblk = (float*)(ws + 16384);
    unsigned short* wt   = (unsigned short*)(ws + 65536);
    unsigned short* xt   = (unsigned short*)(ws + (1u << 20));

    transpose_kernel<<<dim3(HH/4, DD, B_), 256, 0, stream>>>(x, xt);
    pool2_kernel<<<dim3(DD, B_), 256, 0, stream>>>(xt, pblk);
    attn_kernel<<<1, 256, 0, stream>>>(pblk, temperature,
                                       bn1_g, bn1_b, w1, b1,
                                       bn2_g, bn2_b, w2, b2,
                                       bn3_g, bn3_b, w3, b3,
                                       cbias, attn, aggb);
    aggw_kernel<<<(B_*27*COUT*CIN)/256, 256, 0, stream>>>(weight, attn, wt);
    conv_mfma<<<dim3(HH/4, DD/4, B_), 512, 0, stream>>>(xt, wt, aggb, out);
}